// Round 1
// baseline (165.795 us; speedup 1.0000x reference)
//
#include <hip/hip_runtime.h>
#include <math.h>

typedef __attribute__((ext_vector_type(8)))  short short8;
typedef __attribute__((ext_vector_type(16))) float f32x16;

#define NPLANE 48
#define H 512
#define W 512
#define TH 21
#define OH 492
#define OW 492
#define EPSF 1e-8f

#define STRIDE 168   // LDS row stride in shorts (measured ~conflict-free)
#define SEG_ROWS 84  // 64 output rows + 20 halo

// d_ws layout (bytes) — total ~4.13 MB:
//   [0)        B_corr : 48 * 21 * 4 * 512 bf16 = 4,128,768 B (frag-swizzled)
//   [4128768)  B_ones : 4 * 512 bf16 = 4096 B
#define BONES_HOFF (4128768u / 2)

__device__ inline unsigned short f2bf(float f) {
    unsigned u = __float_as_uint(f);
    return (unsigned short)((u + 0x7FFFu + ((u >> 16) & 1u)) >> 16);
}
__device__ inline float bf2f(unsigned s) {
    return __uint_as_float(s << 16);
}
// Packed RNE f32x2 -> bf16x2 (D.lo = bf16(lo), D.hi = bf16(hi)); identical
// rounding to f2bf but 1 VALU op instead of ~9 for a packed pair.
__device__ inline unsigned cvtpk(float lo, float hi) {
    unsigned r;
    asm("v_cvt_pk_bf16_f32 %0, %1, %2" : "=v"(r) : "v"(lo), "v"(hi));
    return r;
}

// ---------------------------------------------------------------------------
// K0: template z-norm (/441 folded) -> Toeplitz B fragments (unchanged).
// ---------------------------------------------------------------------------
__global__ void build_b_kernel(const float* __restrict__ tpl,
                               unsigned short* __restrict__ ws16) {
    __shared__ float sm[2];
    const int plane = blockIdx.x;
    const float* t = tpl + plane * 441;
    const int tid = threadIdx.x;
    if (tid < 64) {
        float s = 0.f, s2 = 0.f;
        for (int k = tid; k < 441; k += 64) {
            float x = t[k];
            s += x; s2 += x * x;
        }
#pragma unroll
        for (int o = 32; o >= 1; o >>= 1) {
            s  += __shfl_down(s, o);
            s2 += __shfl_down(s2, o);
        }
        if (tid == 0) {
            float mean = s / 441.f;
            float var = fmaxf(s2 / 441.f - mean * mean, 0.f);
            sm[0] = mean;
            sm[1] = 1.f / ((sqrtf(var) + EPSF) * 441.f);
        }
    }
    __syncthreads();
    const float mean = sm[0], scale = sm[1];

    unsigned short* bc = ws16 + (size_t)plane * 43008;
    for (int i = tid; i < 43008; i += 256) {
        int j = i & 7, lane = (i >> 3) & 63, s = (i >> 9) & 3, u = i >> 11;
        int k = ((lane >> 5) << 3) + j, n = lane & 31;
        int v = 16 * s + k - n;
        float val = (v >= 0 && v < TH) ? (t[u * 21 + v] - mean) * scale : 0.f;
        bc[i] = f2bf(val);
    }
    if (plane == 0) {
        unsigned short* bo = ws16 + BONES_HOFF;
        const unsigned short one = f2bf(1.f);
        for (int i = tid; i < 2048; i += 256) {
            int j = i & 7, lane = (i >> 3) & 63, s = (i >> 9) & 3;
            int k = ((lane >> 5) << 3) + j, n = lane & 31;
            int v = 16 * s + k - n;
            bo[i] = (v >= 0 && v < TH) ? one : (unsigned short)0;
        }
    }
}

// ---------------------------------------------------------------------------
// K1: fused NCC. R1 changes vs 164-µs baseline:
//  * vbuf shrunk 64 -> 32 rows, box/epilogue split into tr==0 / tr==1 halves
//    -> LDS 49.7 KB -> 38.1 KB -> 4 blocks/CU (__launch_bounds__(256,4)).
//  * vertical passes: 8-row batched LDS reads (pin[8]/pout[8]) to hide
//    ~120-cyc ds_read latency in the dependent sliding-window chain.
//  * v_cvt_pk_bf16_f32 for all f32->bf16x2 packing (stage + passes).
//  * corr u-loop unrolled x2 (ping-pong bA/bB, no register copies).
// ---------------------------------------------------------------------------
__global__ __launch_bounds__(256, 4) void ncc_fused_kernel(
    const float* __restrict__ in, const unsigned short* __restrict__ ws16,
    float* __restrict__ out) {
    __shared__ short seg[SEG_ROWS * STRIDE];   // 28224 B
    __shared__ short vbuf[32 * STRIDE];        // 10752 B  (total 38976 B)

    const int plane = blockIdx.z;
    const int x0 = blockIdx.x * 128;
    const int y0 = blockIdx.y * 64;
    const int tid = threadIdx.x;
    const int lane = tid & 63;
    const int tr = (tid >> 6) & 1;   // tile-row of this wave
    const int tc = tid >> 7;         // tile-col pair of this wave
    const float* src = in + (size_t)plane * H * W;

    // ---- stage 84x160 fp32 -> bf16 into LDS (cvt_pk packing) ----
    for (int i = tid; i < SEG_ROWS * 20; i += 256) {
        int row = i / 20, s8 = i - row * 20;
        int gy = y0 + row, gx = x0 + s8 * 8;
        if (gy < H && gx + 7 < W) {
            float4 a = *(const float4*)(src + gy * W + gx);
            float4 b = *(const float4*)(src + gy * W + gx + 4);
            uint4 v;
            v.x = cvtpk(a.x, a.y);
            v.y = cvtpk(a.z, a.w);
            v.z = cvtpk(b.x, b.y);
            v.w = cvtpk(b.z, b.w);
            *(uint4*)&seg[row * STRIDE + s8 * 8] = v;
        } else {
            short8 val;
#pragma unroll
            for (int e = 0; e < 8; ++e) {
                float xv = (gy < H && gx + e < W) ? src[gy * W + gx + e] : 0.f;
                val[e] = (short)f2bf(xv);
            }
            *(short8*)&seg[row * STRIDE + s8 * 8] = val;
        }
    }
    __syncthreads();

    const int m = lane & 31;
    const int half = lane >> 5;
    const int abase = (tr * 32 + m) * STRIDE + tc * 64 + half * 8;
    const int vbase = m * STRIDE + tc * 64 + half * 8;
    const unsigned short* bc = ws16 + (size_t)plane * 43008 + lane * 8;

    f32x16 acc[2];
#pragma unroll
    for (int t = 0; t < 2; ++t)
#pragma unroll
        for (int e = 0; e < 16; ++e) acc[t][e] = 0.f;

    auto corr_step = [&](int u, short8* bf) {
        short8 af[6];
#pragma unroll
        for (int g = 0; g < 6; ++g)
            af[g] = *(const short8*)&seg[abase + u * STRIDE + g * 16];
#pragma unroll
        for (int t = 0; t < 2; ++t)
#pragma unroll
            for (int s = 0; s < 4; ++s)
                acc[t] = __builtin_amdgcn_mfma_f32_32x32x16_bf16(
                    af[2 * t + s], bf[s], acc[t], 0, 0, 0);
    };

    // ---- corr K-loop, unrolled x2 with ping-pong B buffers ----
    short8 bA[4], bB[4];
#pragma unroll
    for (int s = 0; s < 4; ++s)
        bA[s] = *(const short8*)(bc + s * 512);

    for (int u = 0; u < TH - 1; u += 2) {
#pragma unroll
        for (int s = 0; s < 4; ++s)
            bB[s] = *(const short8*)(bc + ((u + 1) * 4 + s) * 512);
        corr_step(u, bA);
#pragma unroll
        for (int s = 0; s < 4; ++s)
            bA[s] = *(const short8*)(bc + ((u + 2) * 4 + s) * 512);
        corr_step(u + 1, bB);
    }
    corr_step(TH - 1, bA);

    // ---- vertical 21-sum pass over one 32-row half (batched LDS reads) ----
    // Hh: which 32-row half of the block; sq: sum of squares instead of sum.
    auto vpass = [&](int Hh, bool sq) {
        if (tid < 160) {
            const int sub = (tid >= 80) ? 16 : 0;
            const int c2 = (tid % 80) * 2;
            const int base = Hh * 32 + sub;
            float s0 = 0.f, s1 = 0.f;
#pragma unroll
            for (int r = 0; r < 20; ++r) {
                unsigned p = *(const unsigned*)&seg[(base + r) * STRIDE + c2];
                float a = bf2f(p & 0xffffu), b = bf2f(p >> 16);
                if (sq) { s0 = fmaf(a, a, s0); s1 = fmaf(b, b, s1); }
                else    { s0 += a; s1 += b; }
            }
            for (int yb = 0; yb < 16; yb += 8) {
                unsigned pin[8], pout[8];
#pragma unroll
                for (int r = 0; r < 8; ++r) {
                    pin[r]  = *(const unsigned*)
                        &seg[(base + yb + r + 20) * STRIDE + c2];
                    pout[r] = *(const unsigned*)
                        &seg[(base + yb + r) * STRIDE + c2];
                }
#pragma unroll
                for (int r = 0; r < 8; ++r) {
                    float a = bf2f(pin[r] & 0xffffu), b = bf2f(pin[r] >> 16);
                    if (sq) { s0 = fmaf(a, a, s0); s1 = fmaf(b, b, s1); }
                    else    { s0 += a; s1 += b; }
                    *(unsigned*)&vbuf[(sub + yb + r) * STRIDE + c2] =
                        cvtpk(s0, s1);
                    float c = bf2f(pout[r] & 0xffffu), d = bf2f(pout[r] >> 16);
                    if (sq) { s0 = fmaf(-c, c, s0); s1 = fmaf(-d, d, s1); }
                    else    { s0 -= c; s1 -= d; }
                }
            }
        }
    };

    // ---- box sums via ones-Toeplitz MFMA (reads vbuf rows 0..31) ----
    f32x16 aS[2];
    auto box = [&](f32x16* dst) {
        const unsigned short* bo16 = ws16 + BONES_HOFF + lane * 8;
        short8 bn[4];
#pragma unroll
        for (int s = 0; s < 4; ++s)
            bn[s] = *(const short8*)(bo16 + s * 512);
#pragma unroll
        for (int t = 0; t < 2; ++t) {
#pragma unroll
            for (int e = 0; e < 16; ++e) dst[t][e] = 0.f;
#pragma unroll
            for (int s = 0; s < 4; ++s) {
                short8 vf = *(const short8*)&vbuf[vbase + (2 * t + s) * 16];
                dst[t] = __builtin_amdgcn_mfma_f32_32x32x16_bf16(
                    vf, bn[s], dst[t], 0, 0, 0);
            }
        }
    };

    // ---- aQ + normalize + store for this wave's tr half ----
    auto finish = [&]() {
        const unsigned short* bo16 = ws16 + BONES_HOFF + lane * 8;
        short8 bn[4];
#pragma unroll
        for (int s = 0; s < 4; ++s)
            bn[s] = *(const short8*)(bo16 + s * 512);
        const float invn = 1.f / 441.f;
        float* outp = out + (size_t)plane * OH * OW;
#pragma unroll
        for (int t = 0; t < 2; ++t) {
            f32x16 q;
#pragma unroll
            for (int e = 0; e < 16; ++e) q[e] = 0.f;
#pragma unroll
            for (int s = 0; s < 4; ++s) {
                short8 qf = *(const short8*)&vbuf[vbase + (2 * t + s) * 16];
                q = __builtin_amdgcn_mfma_f32_32x32x16_bf16(qf, bn[s], q,
                                                            0, 0, 0);
            }
            const int gx = x0 + tc * 64 + t * 32 + m;
            if (gx < OW) {
#pragma unroll
                for (int r = 0; r < 16; ++r) {
                    int gy = y0 + tr * 32 + (r & 3) + ((r >> 2) << 3) + half * 4;
                    if (gy < OH) {
                        float mean = aS[t][r] * invn;
                        float msq = q[r] * invn;
                        float sd = sqrtf(msq - mean * mean + EPSF);
                        outp[(size_t)gy * OW + gx] = acc[t][r] / (sd + EPSF);
                    }
                }
            }
        }
    };

    // ---- phase schedule over the 32-row vbuf ----
    vpass(0, false);
    __syncthreads();
    if (tr == 0) box(aS);
    __syncthreads();
    vpass(1, false);
    __syncthreads();
    if (tr == 1) box(aS);
    __syncthreads();
    vpass(0, true);
    __syncthreads();
    if (tr == 0) finish();
    __syncthreads();
    vpass(1, true);
    __syncthreads();
    if (tr == 1) finish();
}

extern "C" void kernel_launch(void* const* d_in, const int* in_sizes, int n_in,
                              void* d_out, int out_size, void* d_ws,
                              size_t ws_size, hipStream_t stream) {
    const float* inputs = (const float*)d_in[0];
    const float* tmpl = (const float*)d_in[1];
    float* out = (float*)d_out;
    unsigned short* ws16 = (unsigned short*)d_ws;

    build_b_kernel<<<NPLANE, 256, 0, stream>>>(tmpl, ws16);
    ncc_fused_kernel<<<dim3(4, 8, NPLANE), 256, 0, stream>>>(inputs, ws16, out);
}